// Round 1
// baseline (508.063 us; speedup 1.0000x reference)
//
#include <hip/hip_runtime.h>

// Problem constants (match reference)
#define B_SZ   8
#define NUMR   128            // num
#define L_SZ   (NUMR * NUMR)  // 16384
#define HH     8              // heads
#define DK     64
#define CC     512            // H*DK
#define EPSV   1e-8f

// ---------------------------------------------------------------------------
// Kernel 1: cosine similarity + ReLU.
// One wave (64 lanes) per (b, l) row: each lane loads 8 contiguous floats
// (2 x float4) of q and k -> lane group [h*8, h*8+8) covers head h exactly.
// 8-lane shuffle reduction yields dot/|q||k| per head; lanes 0..7 write the
// 8 head values contiguously into attn (== d_out) in (b,i,j,h) layout.
// Block 0 additionally zeroes the 128-entry column mask in workspace.
// ---------------------------------------------------------------------------
__global__ __launch_bounds__(256) void cos_attn_kernel(
    const float* __restrict__ q, const float* __restrict__ k,
    float* __restrict__ attn, unsigned int* __restrict__ colmask) {
  if (blockIdx.x == 0 && threadIdx.x < NUMR) colmask[threadIdx.x] = 0u;

  const int wave = (blockIdx.x * blockDim.x + threadIdx.x) >> 6;  // b*L + l
  const int lane = threadIdx.x & 63;

  const size_t rowbase = (size_t)wave * CC + (size_t)lane * 8;
  const float4* qp = (const float4*)(q + rowbase);
  const float4* kp = (const float4*)(k + rowbase);
  const float4 a0 = qp[0], a1 = qp[1];
  const float4 b0 = kp[0], b1 = kp[1];

  float dot = a0.x * b0.x + a0.y * b0.y + a0.z * b0.z + a0.w * b0.w +
              a1.x * b1.x + a1.y * b1.y + a1.z * b1.z + a1.w * b1.w;
  float qq  = a0.x * a0.x + a0.y * a0.y + a0.z * a0.z + a0.w * a0.w +
              a1.x * a1.x + a1.y * a1.y + a1.z * a1.z + a1.w * a1.w;
  float kk  = b0.x * b0.x + b0.y * b0.y + b0.z * b0.z + b0.w * b0.w +
              b1.x * b1.x + b1.y * b1.y + b1.z * b1.z + b1.w * b1.w;

#pragma unroll
  for (int off = 1; off < 8; off <<= 1) {
    dot += __shfl_xor(dot, off, 64);
    qq  += __shfl_xor(qq,  off, 64);
    kk  += __shfl_xor(kk,  off, 64);
  }

  const float denom = fmaxf(sqrtf(qq) * sqrtf(kk), EPSV);
  const float val   = fmaxf(dot / denom, 0.0f);

  // gather head h's value (resident on lanes h*8..h*8+7) to lane h
  const float r = __shfl(val, (lane & 7) * 8, 64);
  if (lane < 8) attn[(size_t)wave * HH + lane] = r;
}

// ---------------------------------------------------------------------------
// Kernel 2: per-(b, i, h) top-4 over j in [0,128), union into colmask.
// One wave per group; lane holds j=lane and j=lane+64. 4 rounds of
// argmax-with-tiebreak (higher value wins; equal value -> lower index wins,
// matching jax.lax.top_k stable descending semantics).
// ---------------------------------------------------------------------------
__global__ __launch_bounds__(256) void topk_kernel(
    const float* __restrict__ attn, unsigned int* __restrict__ colmask) {
  const int wave = (blockIdx.x * blockDim.x + threadIdx.x) >> 6;  // (b*num+i)*8+h
  const int lane = threadIdx.x & 63;

  const size_t base = (size_t)(wave >> 3) * (NUMR * HH) + (size_t)(wave & 7);
  float v0 = attn[base + (size_t)lane * HH];
  float v1 = attn[base + (size_t)(lane + 64) * HH];

#pragma unroll
  for (int rnd = 0; rnd < 4; ++rnd) {
    float bv;
    int bi;
    if (v1 > v0) { bv = v1; bi = lane + 64; } else { bv = v0; bi = lane; }
#pragma unroll
    for (int off = 1; off < 64; off <<= 1) {
      const float ov = __shfl_xor(bv, off, 64);
      const int   oi = __shfl_xor(bi, off, 64);
      if (ov > bv || (ov == bv && oi < bi)) { bv = ov; bi = oi; }
    }
    // bi now identical on all lanes: the round's winner
    if (bi == lane)            v0 = -1.0f;
    else if (bi == lane + 64)  v1 = -1.0f;
    if (lane == 0) colmask[bi] = 1u;  // racing identical writes: benign
  }
}

// ---------------------------------------------------------------------------
// Kernel 3: out[b,i,j,h] *= roi[b,i,j] * colmask[j]  (in place on d_out)
// One thread per (b,i,j): 8 head values as 2 x float4.
// ---------------------------------------------------------------------------
__global__ __launch_bounds__(256) void apply_kernel(
    float* __restrict__ out, const float* __restrict__ roi,
    const unsigned int* __restrict__ colmask) {
  const int t = blockIdx.x * blockDim.x + threadIdx.x;  // (b*num+i)*num+j
  const float s = roi[t] * (colmask[t & (NUMR - 1)] ? 1.0f : 0.0f);
  float4* p = (float4*)(out + (size_t)t * 8);
  float4 x0 = p[0], x1 = p[1];
  x0.x *= s; x0.y *= s; x0.z *= s; x0.w *= s;
  x1.x *= s; x1.y *= s; x1.z *= s; x1.w *= s;
  p[0] = x0;
  p[1] = x1;
}

extern "C" void kernel_launch(void* const* d_in, const int* in_sizes, int n_in,
                              void* d_out, int out_size, void* d_ws, size_t ws_size,
                              hipStream_t stream) {
  const float* q   = (const float*)d_in[0];  // (B, num, num, C) fp32
  const float* k   = (const float*)d_in[1];  // (B, num, num, C) fp32
  const float* roi = (const float*)d_in[2];  // (B, num, num)    fp32
  float* out = (float*)d_out;                // (B, num, num, H) fp32 == attn scratch
  unsigned int* colmask = (unsigned int*)d_ws;  // 128 entries

  // Kernel 1: B*L = 131072 waves, 4 waves/block -> 32768 blocks
  cos_attn_kernel<<<(B_SZ * L_SZ) / 4, 256, 0, stream>>>(q, k, out, colmask);

  // Kernel 2: B*num*H = 8192 waves -> 2048 blocks
  topk_kernel<<<(B_SZ * NUMR * HH) / 4, 256, 0, stream>>>(out, colmask);

  // Kernel 3: B*num*num = 131072 threads -> 512 blocks
  apply_kernel<<<(B_SZ * L_SZ) / 256, 256, 0, stream>>>(out, roi, colmask);
}